// Round 8
// baseline (122.772 us; speedup 1.0000x reference)
//
#include <hip/hip_runtime.h>

#define B_ 256
#define M_ 512
#define N_ 256
#define K_ 16
#define TROWS 256            // rows per block tile
#define NC 16                // n-cols per chunk
#define NPHASE (N_ / NC)     // 16
#define NBLK (B_ * 2)        // 512 blocks, all co-resident (2/CU, cap 4/CU)

// direct global->LDS, 16B per lane, no VGPR staging
__device__ __forceinline__ void gload_lds16(const float* g, float* l) {
    __builtin_amdgcn_global_load_lds(
        (const __attribute__((address_space(1))) void*)g,
        (__attribute__((address_space(3))) void*)l,
        16, 0, 0);
}

// Fused FM kernel. grid = 512, block = 256 threads (4 waves).
// Wave kq (=t>>6) owns k-quad [kq*4, kq*4+4) -> v reads are wave-uniform
// (SGPR path, zero LDS traffic for v). Lane rs (=t&63) owns rows
// {rs, rs+64, rs+128, rs+192} of the block's 256-row tile.
// After the x-streaming loop, xv lives entirely in registers (a0..a3);
// a device-scope grid barrier publishes per-block sv partials, then the
// pairwise term is computed in-register. No xv round-trip, no second pass.
__global__ __launch_bounds__(256) void fm_fused(
    const float* __restrict__ x, const float* __restrict__ w,
    const float* __restrict__ bias, const float* __restrict__ v,
    float* __restrict__ svpart, int* __restrict__ counter,
    float* __restrict__ out)
{
    __shared__ __align__(16) unsigned char xT[2][TROWS * NC * 4]; // 2 x 16 KiB

    const int t   = threadIdx.x;
    const int rs  = t & 63;
    const int kq  = __builtin_amdgcn_readfirstlane(t >> 6);  // wave-uniform
    const int blk = blockIdx.x;
    const int b   = blk >> 1;
    const int m0  = (blk & 1) * TROWS;

    const float* xb = x + ((size_t)b * M_ + m0) * N_;

    // staging (proven R7 pattern): round i covers rows 64i..64i+63, 64 B/row.
    // LDS dest linear (lane*16B); source col-quad pre-swizzled with the same
    // XOR used on the read side.
    const int srow = t >> 2;                       // 0..63
    const int sq   = (t & 3) ^ ((srow >> 1) & 3);  // swizzled source col-quad
    const int wofs = (t & 192) * 16;               // wave-uniform segment base

    float4 a0 = {0,0,0,0}, a1 = {0,0,0,0}, a2 = {0,0,0,0}, a3 = {0,0,0,0};
    float l0 = 0.f, l1 = 0.f, l2 = 0.f, l3 = 0.f;  // linear term (wave 0)

    const int qx = (rs >> 1) & 3;
    const unsigned char* const xr0 = xT[0] + rs * 64;

    // prologue: phase 0 -> buf 0
    #pragma unroll
    for (int i = 0; i < 4; ++i)
        gload_lds16(xb + (size_t)(srow + 64 * i) * N_ + sq * 4,
                    (float*)(xT[0] + i * 4096 + wofs));
    __syncthreads();

    for (int p = 0; p < NPHASE; ++p) {
        // issue next phase's loads (async) into the other buffer
        if (p + 1 < NPHASE) {
            const float* src = xb + (p + 1) * NC + sq * 4;
            unsigned char* dst = xT[(p + 1) & 1];
            #pragma unroll
            for (int i = 0; i < 4; ++i)
                gload_lds16(src + (size_t)(srow + 64 * i) * N_,
                            (float*)(dst + i * 4096 + wofs));
        }

        const unsigned char* const xr = xr0 + ((p & 1) ? (TROWS * NC * 4) : 0);
        const float* vp = v + (size_t)(p * NC) * K_ + kq * 4;   // wave-uniform

        #pragma unroll
        for (int q = 0; q < NC / 4; ++q) {
            const int qoff = ((q ^ qx) << 4);
            const float4 x0 = *(const float4*)(xr +         qoff);
            const float4 x1 = *(const float4*)(xr +  4096 + qoff);
            const float4 x2 = *(const float4*)(xr +  8192 + qoff);
            const float4 x3 = *(const float4*)(xr + 12288 + qoff);
            // wave-uniform v loads -> s_load (no LDS, no per-lane VMEM)
            const float4 v0 = *(const float4*)(vp + (q * 4 + 0) * K_);
            const float4 v1 = *(const float4*)(vp + (q * 4 + 1) * K_);
            const float4 v2 = *(const float4*)(vp + (q * 4 + 2) * K_);
            const float4 v3 = *(const float4*)(vp + (q * 4 + 3) * K_);

            a0.x += x0.x*v0.x + x0.y*v1.x + x0.z*v2.x + x0.w*v3.x;
            a0.y += x0.x*v0.y + x0.y*v1.y + x0.z*v2.y + x0.w*v3.y;
            a0.z += x0.x*v0.z + x0.y*v1.z + x0.z*v2.z + x0.w*v3.z;
            a0.w += x0.x*v0.w + x0.y*v1.w + x0.z*v2.w + x0.w*v3.w;

            a1.x += x1.x*v0.x + x1.y*v1.x + x1.z*v2.x + x1.w*v3.x;
            a1.y += x1.x*v0.y + x1.y*v1.y + x1.z*v2.y + x1.w*v3.y;
            a1.z += x1.x*v0.z + x1.y*v1.z + x1.z*v2.z + x1.w*v3.z;
            a1.w += x1.x*v0.w + x1.y*v1.w + x1.z*v2.w + x1.w*v3.w;

            a2.x += x2.x*v0.x + x2.y*v1.x + x2.z*v2.x + x2.w*v3.x;
            a2.y += x2.x*v0.y + x2.y*v1.y + x2.z*v2.y + x2.w*v3.y;
            a2.z += x2.x*v0.z + x2.y*v1.z + x2.z*v2.z + x2.w*v3.z;
            a2.w += x2.x*v0.w + x2.y*v1.w + x2.z*v2.w + x2.w*v3.w;

            a3.x += x3.x*v0.x + x3.y*v1.x + x3.z*v2.x + x3.w*v3.x;
            a3.y += x3.x*v0.y + x3.y*v1.y + x3.z*v2.y + x3.w*v3.y;
            a3.z += x3.x*v0.z + x3.y*v1.z + x3.z*v2.z + x3.w*v3.z;
            a3.w += x3.x*v0.w + x3.y*v1.w + x3.z*v2.w + x3.w*v3.w;

            if (kq == 0) {   // wave-uniform branch: only wave 0 runs this
                const float4 wq = *(const float4*)(w + p * NC + q * 4);
                l0 += x0.x*wq.x + x0.y*wq.y + x0.z*wq.z + x0.w*wq.w;
                l1 += x1.x*wq.x + x1.y*wq.y + x1.z*wq.z + x1.w*wq.w;
                l2 += x2.x*wq.x + x2.y*wq.y + x2.z*wq.z + x2.w*wq.w;
                l3 += x3.x*wq.x + x3.y*wq.y + x3.z*wq.z + x3.w*wq.w;
            }
        }
        __syncthreads();   // drains vmcnt: next tile ready, buffers safe
    }

    // ---- per-block sv partial: sum over this block's 256 rows (k-quad kq) ----
    float4 s = {a0.x + a1.x + a2.x + a3.x,
                a0.y + a1.y + a2.y + a3.y,
                a0.z + a1.z + a2.z + a3.z,
                a0.w + a1.w + a2.w + a3.w};
    #pragma unroll
    for (int off = 1; off < 64; off <<= 1) {
        s.x += __shfl_xor(s.x, off);
        s.y += __shfl_xor(s.y, off);
        s.z += __shfl_xor(s.z, off);
        s.w += __shfl_xor(s.w, off);
    }
    if (rs == 0) {   // lane 0 of each wave publishes its k-quad partial
        float* dst = svpart + (size_t)blk * 16 + kq * 4;
        __hip_atomic_store(&dst[0], s.x, __ATOMIC_RELEASE, __HIP_MEMORY_SCOPE_AGENT);
        __hip_atomic_store(&dst[1], s.y, __ATOMIC_RELEASE, __HIP_MEMORY_SCOPE_AGENT);
        __hip_atomic_store(&dst[2], s.z, __ATOMIC_RELEASE, __HIP_MEMORY_SCOPE_AGENT);
        __hip_atomic_store(&dst[3], s.w, __ATOMIC_RELEASE, __HIP_MEMORY_SCOPE_AGENT);
    }
    __syncthreads();

    // ---- grid barrier (all 512 blocks co-resident by construction) ----
    if (t == 0) {
        __hip_atomic_fetch_add(counter, 1, __ATOMIC_ACQ_REL, __HIP_MEMORY_SCOPE_AGENT);
        while (__hip_atomic_load(counter, __ATOMIC_ACQUIRE, __HIP_MEMORY_SCOPE_AGENT) < NBLK)
            __builtin_amdgcn_s_sleep(1);
    }
    __syncthreads();

    // ---- sv for batch b: both block partials, fixed order (deterministic) ----
    const float* p0p = svpart + (size_t)(b * 2 + 0) * 16 + kq * 4;
    const float* p1p = svpart + (size_t)(b * 2 + 1) * 16 + kq * 4;
    float4 sv;
    sv.x = __hip_atomic_load(&p0p[0], __ATOMIC_RELAXED, __HIP_MEMORY_SCOPE_AGENT)
         + __hip_atomic_load(&p1p[0], __ATOMIC_RELAXED, __HIP_MEMORY_SCOPE_AGENT);
    sv.y = __hip_atomic_load(&p0p[1], __ATOMIC_RELAXED, __HIP_MEMORY_SCOPE_AGENT)
         + __hip_atomic_load(&p1p[1], __ATOMIC_RELAXED, __HIP_MEMORY_SCOPE_AGENT);
    sv.z = __hip_atomic_load(&p0p[2], __ATOMIC_RELAXED, __HIP_MEMORY_SCOPE_AGENT)
         + __hip_atomic_load(&p1p[2], __ATOMIC_RELAXED, __HIP_MEMORY_SCOPE_AGENT);
    sv.w = __hip_atomic_load(&p0p[3], __ATOMIC_RELAXED, __HIP_MEMORY_SCOPE_AGENT)
         + __hip_atomic_load(&p1p[3], __ATOMIC_RELAXED, __HIP_MEMORY_SCOPE_AGENT);

    // ---- pairwise term from registers; cross-wave (k) reduce via LDS ----
    float* pld = (float*)xT;   // [4][256] floats, xT no longer needed
    const float q0 = a0.x*(sv.x - a0.x) + a0.y*(sv.y - a0.y) + a0.z*(sv.z - a0.z) + a0.w*(sv.w - a0.w);
    const float q1 = a1.x*(sv.x - a1.x) + a1.y*(sv.y - a1.y) + a1.z*(sv.z - a1.z) + a1.w*(sv.w - a1.w);
    const float q2 = a2.x*(sv.x - a2.x) + a2.y*(sv.y - a2.y) + a2.z*(sv.z - a2.z) + a2.w*(sv.w - a2.w);
    const float q3 = a3.x*(sv.x - a3.x) + a3.y*(sv.y - a3.y) + a3.z*(sv.z - a3.z) + a3.w*(sv.w - a3.w);
    pld[kq * 256 +   0 + rs] = q0;
    pld[kq * 256 +  64 + rs] = q1;
    pld[kq * 256 + 128 + rs] = q2;
    pld[kq * 256 + 192 + rs] = q3;
    __syncthreads();

    if (kq == 0) {
        const float bias0 = bias[0];
        float* ob = out + (size_t)b * M_ + m0;
        #pragma unroll
        for (int j = 0; j < 4; ++j) {
            const int r = 64 * j + rs;
            const float lv = (j == 0) ? l0 : (j == 1) ? l1 : (j == 2) ? l2 : l3;
            ob[r] = lv + bias0 + 0.5f * (pld[r] + pld[256 + r] + pld[512 + r] + pld[768 + r]);
        }
    }
}

extern "C" void kernel_launch(void* const* d_in, const int* in_sizes, int n_in,
                              void* d_out, int out_size, void* d_ws, size_t ws_size,
                              hipStream_t stream) {
    const float* x    = (const float*)d_in[0];
    const float* w    = (const float*)d_in[1];
    const float* bias = (const float*)d_in[2];
    const float* v    = (const float*)d_in[3];
    float* out = (float*)d_out;

    float* svpart = (float*)d_ws;                       // NBLK*16 floats = 32 KiB
    int*   counter = (int*)((char*)d_ws + (64 << 10));  // own cacheline region

    hipMemsetAsync(counter, 0, sizeof(int), stream);    // reset barrier each launch
    fm_fused<<<dim3(NBLK), dim3(256), 0, stream>>>(x, w, bias, v, svpart, counter, out);
}

// Round 9
// 109.467 us; speedup vs baseline: 1.1215x; 1.1215x over previous
//
#include <hip/hip_runtime.h>

#define B_ 256
#define M_ 512
#define N_ 256
#define K_ 16
#define TROWS 256            // rows per block tile
#define NC 16                // n-cols per chunk
#define NPHASE (N_ / NC)     // 16
#define NBLK (B_ * 2)        // 512 blocks: 2/CU, LDS cap 3/CU -> co-resident w/ slack

// direct global->LDS, 16B per lane, no VGPR staging
__device__ __forceinline__ void gload_lds16(const float* g, float* l) {
    __builtin_amdgcn_global_load_lds(
        (const __attribute__((address_space(1))) void*)g,
        (__attribute__((address_space(3))) void*)l,
        16, 0, 0);
}

// Fused FM kernel, R7 mapping + counted-vmcnt pipeline + register-xv epilogue.
// grid = 512, block = 256. Thread t = (rs = t>>2 in 0..63, ksub = t&3):
// owns rows {rs, rs+64, rs+128, rs+192}, k-quad [ksub*4, +4).
// x-reads: 16 rows/wave, 4-lane broadcast -> conflict-free (R6/R7 proven).
// Pipeline: issue phase p+1 loads, s_waitcnt vmcnt(4) (p's landed, p+1 in
// flight), raw s_barrier (NO vmcnt(0) drain - prefetch crosses the barrier).
__global__ __launch_bounds__(256) void fm_fused(
    const float* __restrict__ x, const float* __restrict__ w,
    const float* __restrict__ bias, const float* __restrict__ v,
    float* __restrict__ svpart, int* __restrict__ counter,
    float* __restrict__ out)
{
    __shared__ __align__(16) float vL[N_][K_];                    // 16 KiB
    __shared__ __align__(16) float wL[N_];                        // 1 KiB
    __shared__ __align__(16) unsigned char xT[2][TROWS * NC * 4]; // 2 x 16 KiB
    __shared__ __align__(16) float red[64];

    const int t    = threadIdx.x;
    const int rs   = t >> 2;        // 0..63
    const int ksub = t & 3;
    const int blk  = blockIdx.x;
    const int b    = blk >> 1;
    const int m0   = (blk & 1) * TROWS;

    // stage v (4096 floats) and w (256 floats) once
    {
        const float4* v4 = (const float4*)v;
        float4* vL4 = (float4*)&vL[0][0];
        #pragma unroll
        for (int i = 0; i < 4; ++i) vL4[t + 256 * i] = v4[t + 256 * i];
        wL[t] = w[t];
    }

    const float* xb = x + ((size_t)b * M_ + m0) * N_;

    // staging (R7 exact): round i covers rows 64i..64i+63, 64 B/row.
    // LDS dest linear (wave base + lane*16); source col-quad pre-swizzled with
    // the read-side XOR.
    const int srow = t >> 2;                       // 0..63
    const int sq   = (t & 3) ^ ((srow >> 1) & 3);  // swizzled source col-quad
    const int wofs = (t & 192) * 16;               // wave-uniform segment base

    float4 a0 = {0,0,0,0}, a1 = {0,0,0,0}, a2 = {0,0,0,0}, a3 = {0,0,0,0};
    float l0 = 0.f, l1 = 0.f, l2 = 0.f, l3 = 0.f;  // linear term (ksub==0)

    const int qx = (rs >> 1) & 3;
    const unsigned char* const xr0 = xT[0] + rs * 64;
    const float bias0 = bias[0];

    // prologue: phase 0 -> buf 0 (4 loads/thread)
    #pragma unroll
    for (int i = 0; i < 4; ++i)
        gload_lds16(xb + (size_t)(srow + 64 * i) * N_ + sq * 4,
                    (float*)(xT[0] + i * 4096 + wofs));
    asm volatile("s_waitcnt lgkmcnt(0)" ::: "memory");   // v/w ds_writes done

    for (int p = 0; p < NPHASE; ++p) {
        // issue next phase's loads (stay in flight across both barriers)
        if (p + 1 < NPHASE) {
            const float* src = xb + (p + 1) * NC + sq * 4;
            unsigned char* dst = xT[(p + 1) & 1];
            #pragma unroll
            for (int i = 0; i < 4; ++i)
                gload_lds16(src + (size_t)(srow + 64 * i) * N_,
                            (float*)(dst + i * 4096 + wofs));
            asm volatile("s_waitcnt vmcnt(4)" ::: "memory");  // p's 4 landed
        } else {
            asm volatile("s_waitcnt vmcnt(0)" ::: "memory");
        }
        __builtin_amdgcn_s_barrier();           // tile p visible block-wide
        asm volatile("" ::: "memory");

        const unsigned char* const xr = xr0 + ((p & 1) ? (TROWS * NC * 4) : 0);
        #pragma unroll
        for (int q = 0; q < NC / 4; ++q) {
            const int qoff = ((q ^ qx) << 4);
            const float4 x0 = *(const float4*)(xr +         qoff);
            const float4 x1 = *(const float4*)(xr +  4096 + qoff);
            const float4 x2 = *(const float4*)(xr +  8192 + qoff);
            const float4 x3 = *(const float4*)(xr + 12288 + qoff);
            const int n0 = p * NC + q * 4;
            const float4 v0 = *(const float4*)&vL[n0 + 0][ksub * 4];
            const float4 v1 = *(const float4*)&vL[n0 + 1][ksub * 4];
            const float4 v2 = *(const float4*)&vL[n0 + 2][ksub * 4];
            const float4 v3 = *(const float4*)&vL[n0 + 3][ksub * 4];

            a0.x += x0.x*v0.x + x0.y*v1.x + x0.z*v2.x + x0.w*v3.x;
            a0.y += x0.x*v0.y + x0.y*v1.y + x0.z*v2.y + x0.w*v3.y;
            a0.z += x0.x*v0.z + x0.y*v1.z + x0.z*v2.z + x0.w*v3.z;
            a0.w += x0.x*v0.w + x0.y*v1.w + x0.z*v2.w + x0.w*v3.w;

            a1.x += x1.x*v0.x + x1.y*v1.x + x1.z*v2.x + x1.w*v3.x;
            a1.y += x1.x*v0.y + x1.y*v1.y + x1.z*v2.y + x1.w*v3.y;
            a1.z += x1.x*v0.z + x1.y*v1.z + x1.z*v2.z + x1.w*v3.z;
            a1.w += x1.x*v0.w + x1.y*v1.w + x1.z*v2.w + x1.w*v3.w;

            a2.x += x2.x*v0.x + x2.y*v1.x + x2.z*v2.x + x2.w*v3.x;
            a2.y += x2.x*v0.y + x2.y*v1.y + x2.z*v2.y + x2.w*v3.y;
            a2.z += x2.x*v0.z + x2.y*v1.z + x2.z*v2.z + x2.w*v3.z;
            a2.w += x2.x*v0.w + x2.y*v1.w + x2.z*v2.w + x2.w*v3.w;

            a3.x += x3.x*v0.x + x3.y*v1.x + x3.z*v2.x + x3.w*v3.x;
            a3.y += x3.x*v0.y + x3.y*v1.y + x3.z*v2.y + x3.w*v3.y;
            a3.z += x3.x*v0.z + x3.y*v1.z + x3.z*v2.z + x3.w*v3.z;
            a3.w += x3.x*v0.w + x3.y*v1.w + x3.z*v2.w + x3.w*v3.w;

            if (ksub == 0) {
                const float4 wq = *(const float4*)&wL[n0];
                l0 += x0.x*wq.x + x0.y*wq.y + x0.z*wq.z + x0.w*wq.w;
                l1 += x1.x*wq.x + x1.y*wq.y + x1.z*wq.z + x1.w*wq.w;
                l2 += x2.x*wq.x + x2.y*wq.y + x2.z*wq.z + x2.w*wq.w;
                l3 += x3.x*wq.x + x3.y*wq.y + x3.z*wq.z + x3.w*wq.w;
            }
        }
        asm volatile("" ::: "memory");
        __builtin_amdgcn_s_barrier();   // reads of buf p done; overwrite ok
        asm volatile("" ::: "memory");
    }

    // ---- per-block sv partial (k-quad ksub): sum 4 own rows + butterfly ----
    float4 s = {a0.x + a1.x + a2.x + a3.x,
                a0.y + a1.y + a2.y + a3.y,
                a0.z + a1.z + a2.z + a3.z,
                a0.w + a1.w + a2.w + a3.w};
    #pragma unroll
    for (int off = 4; off < 64; off <<= 1) {
        s.x += __shfl_xor(s.x, off);
        s.y += __shfl_xor(s.y, off);
        s.z += __shfl_xor(s.z, off);
        s.w += __shfl_xor(s.w, off);
    }
    const int wave = t >> 6;
    if ((t & 63) < 4)
        *(float4*)(red + wave * 16 + ksub * 4) = s;
    __syncthreads();
    if (t < 16) {
        const float sv16 = red[t] + red[16 + t] + red[32 + t] + red[48 + t];
        __hip_atomic_store(svpart + (size_t)blk * 16 + t, sv16,
                           __ATOMIC_RELEASE, __HIP_MEMORY_SCOPE_AGENT);
    }
    __syncthreads();   // drains vmcnt -> svpart stores complete before signal

    // ---- grid barrier (512 blocks, 2/CU vs cap 3 -> co-resident) ----
    if (t == 0) {
        __hip_atomic_fetch_add(counter, 1, __ATOMIC_ACQ_REL, __HIP_MEMORY_SCOPE_AGENT);
        while (__hip_atomic_load(counter, __ATOMIC_ACQUIRE, __HIP_MEMORY_SCOPE_AGENT) < NBLK)
            __builtin_amdgcn_s_sleep(2);
    }
    __syncthreads();

    // ---- sv for batch b (fixed order), pairwise term from registers ----
    float4 sv = {0, 0, 0, 0};
    #pragma unroll
    for (int j = 0; j < 2; ++j) {
        const float* pp = svpart + (size_t)(b * 2 + j) * 16 + ksub * 4;
        sv.x += __hip_atomic_load(&pp[0], __ATOMIC_RELAXED, __HIP_MEMORY_SCOPE_AGENT);
        sv.y += __hip_atomic_load(&pp[1], __ATOMIC_RELAXED, __HIP_MEMORY_SCOPE_AGENT);
        sv.z += __hip_atomic_load(&pp[2], __ATOMIC_RELAXED, __HIP_MEMORY_SCOPE_AGENT);
        sv.w += __hip_atomic_load(&pp[3], __ATOMIC_RELAXED, __HIP_MEMORY_SCOPE_AGENT);
    }

    float q0 = a0.x*(sv.x - a0.x) + a0.y*(sv.y - a0.y) + a0.z*(sv.z - a0.z) + a0.w*(sv.w - a0.w);
    float q1 = a1.x*(sv.x - a1.x) + a1.y*(sv.y - a1.y) + a1.z*(sv.z - a1.z) + a1.w*(sv.w - a1.w);
    float q2 = a2.x*(sv.x - a2.x) + a2.y*(sv.y - a2.y) + a2.z*(sv.z - a2.z) + a2.w*(sv.w - a2.w);
    float q3 = a3.x*(sv.x - a3.x) + a3.y*(sv.y - a3.y) + a3.z*(sv.z - a3.z) + a3.w*(sv.w - a3.w);
    // cross-ksub reduce: lanes t = 4*rs + ksub -> xor over bits 0,1
    q0 += __shfl_xor(q0, 1); q0 += __shfl_xor(q0, 2);
    q1 += __shfl_xor(q1, 1); q1 += __shfl_xor(q1, 2);
    q2 += __shfl_xor(q2, 1); q2 += __shfl_xor(q2, 2);
    q3 += __shfl_xor(q3, 1); q3 += __shfl_xor(q3, 2);

    if (ksub == 0) {
        float* ob = out + (size_t)b * M_ + m0 + rs;
        ob[0]   = l0 + bias0 + 0.5f * q0;
        ob[64]  = l1 + bias0 + 0.5f * q1;
        ob[128] = l2 + bias0 + 0.5f * q2;
        ob[192] = l3 + bias0 + 0.5f * q3;
    }
}

extern "C" void kernel_launch(void* const* d_in, const int* in_sizes, int n_in,
                              void* d_out, int out_size, void* d_ws, size_t ws_size,
                              hipStream_t stream) {
    const float* x    = (const float*)d_in[0];
    const float* w    = (const float*)d_in[1];
    const float* bias = (const float*)d_in[2];
    const float* v    = (const float*)d_in[3];
    float* out = (float*)d_out;

    float* svpart  = (float*)d_ws;                       // 512*16 floats = 32 KiB
    int*   counter = (int*)((char*)d_ws + (128 << 10));  // separate region

    hipMemsetAsync(counter, 0, sizeof(int), stream);     // reset barrier each launch
    fm_fused<<<dim3(NBLK), dim3(256), 0, stream>>>(x, w, bias, v, svpart, counter, out);
}

// Round 10
// 43.856 us; speedup vs baseline: 2.7994x; 2.4960x over previous
//
#include <hip/hip_runtime.h>

#define B_ 256
#define M_ 512
#define N_ 256
#define K_ 16
#define TROWS 256            // rows per block tile
#define NC 16                // n-cols per chunk
#define NPHASE (N_ / NC)     // 16

// direct global->LDS, 16B per lane, no VGPR staging
__device__ __forceinline__ void gload_lds16(const float* g, float* l) {
    __builtin_amdgcn_global_load_lds(
        (const __attribute__((address_space(1))) void*)g,
        (__attribute__((address_space(3))) void*)l,
        16, 0, 0);
}

// ---------------- Pass 1 ----------------
// R7 geometry/mapping (proven conflict-free, clean traffic) + counted-vmcnt
// pipeline: phase p+1's global_load_lds stay in flight across the barrier;
// only vmcnt(4) (phase p's 4 loads landed) is enforced before compute.
// grid = B_*2 = 512 blocks, 256 threads.
// Thread t = (rs = t>>2 in 0..63, ksub = t&3): owns rows {rs, rs+64, rs+128,
// rs+192}, k-quad [ksub*4, +4). x-reads are 16-row/wave 4-lane-broadcast.
__global__ __launch_bounds__(256) void fm_pass1(
    const float* __restrict__ x, const float* __restrict__ w,
    const float* __restrict__ bias, const float* __restrict__ v,
    float* __restrict__ xv, float* __restrict__ svpart, float* __restrict__ out)
{
    __shared__ __align__(16) float vL[N_][K_];                   // 16 KiB
    __shared__ __align__(16) float wL[N_];                       // 1 KiB
    __shared__ __align__(16) unsigned char xT[2][TROWS * NC * 4];// 2 x 16 KiB
    __shared__ __align__(16) float red[64];                      // sv partials

    const int t    = threadIdx.x;
    const int rs   = t >> 2;        // 0..63
    const int ksub = t & 3;
    const int blk  = blockIdx.x;
    const int b    = blk >> 1;
    const int m0   = (blk & 1) * TROWS;

    // stage v (4096 floats) and w (256 floats) once
    {
        const float4* v4 = (const float4*)v;
        float4* vL4 = (float4*)&vL[0][0];
        #pragma unroll
        for (int i = 0; i < 4; ++i) vL4[t + 256 * i] = v4[t + 256 * i];
        wL[t] = w[t];
    }

    const float* xb = x + ((size_t)b * M_ + m0) * N_;

    // staging (R7 exact): round i covers rows 64i..64i+63, 64 B per row.
    // LDS dest linear (wave base + lane*16); source col-quad pre-swizzled with
    // the same XOR used on the read side.
    const int srow = t >> 2;                       // 0..63
    const int sq   = (t & 3) ^ ((srow >> 1) & 3);  // swizzled source col-quad
    const int wofs = (t & 192) * 16;               // wave-uniform segment base

    float4 a0 = {0,0,0,0}, a1 = {0,0,0,0}, a2 = {0,0,0,0}, a3 = {0,0,0,0};
    float l0 = 0.f, l1 = 0.f, l2 = 0.f, l3 = 0.f;  // linear term (ksub==0)

    const int qx = (rs >> 1) & 3;
    const unsigned char* const xr0 = xT[0] + rs * 64;
    const float bias0 = bias[0];

    // prologue: phase 0 -> buf 0 (4 loads/thread)
    #pragma unroll
    for (int i = 0; i < 4; ++i)
        gload_lds16(xb + (size_t)(srow + 64 * i) * N_ + sq * 4,
                    (float*)(xT[0] + i * 4096 + wofs));
    asm volatile("s_waitcnt lgkmcnt(0)" ::: "memory");   // v/w ds_writes done

    for (int p = 0; p < NPHASE; ++p) {
        // issue next phase's loads (they stay in flight across the barrier)
        if (p + 1 < NPHASE) {
            const float* src = xb + (p + 1) * NC + sq * 4;
            unsigned char* dst = xT[(p + 1) & 1];
            #pragma unroll
            for (int i = 0; i < 4; ++i)
                gload_lds16(src + (size_t)(srow + 64 * i) * N_,
                            (float*)(dst + i * 4096 + wofs));
            asm volatile("s_waitcnt vmcnt(4)" ::: "memory");  // p's 4 landed
        } else {
            asm volatile("s_waitcnt vmcnt(0)" ::: "memory");
        }
        __builtin_amdgcn_s_barrier();           // tile p visible block-wide
        asm volatile("" ::: "memory");

        const unsigned char* const xr = xr0 + ((p & 1) ? (TROWS * NC * 4) : 0);
        #pragma unroll
        for (int q = 0; q < NC / 4; ++q) {
            const int qoff = ((q ^ qx) << 4);
            const float4 x0 = *(const float4*)(xr +         qoff);
            const float4 x1 = *(const float4*)(xr +  4096 + qoff);
            const float4 x2 = *(const float4*)(xr +  8192 + qoff);
            const float4 x3 = *(const float4*)(xr + 12288 + qoff);
            const int n0 = p * NC + q * 4;
            const float4 v0 = *(const float4*)&vL[n0 + 0][ksub * 4];
            const float4 v1 = *(const float4*)&vL[n0 + 1][ksub * 4];
            const float4 v2 = *(const float4*)&vL[n0 + 2][ksub * 4];
            const float4 v3 = *(const float4*)&vL[n0 + 3][ksub * 4];

            a0.x += x0.x*v0.x + x0.y*v1.x + x0.z*v2.x + x0.w*v3.x;
            a0.y += x0.x*v0.y + x0.y*v1.y + x0.z*v2.y + x0.w*v3.y;
            a0.z += x0.x*v0.z + x0.y*v1.z + x0.z*v2.z + x0.w*v3.z;
            a0.w += x0.x*v0.w + x0.y*v1.w + x0.z*v2.w + x0.w*v3.w;

            a1.x += x1.x*v0.x + x1.y*v1.x + x1.z*v2.x + x1.w*v3.x;
            a1.y += x1.x*v0.y + x1.y*v1.y + x1.z*v2.y + x1.w*v3.y;
            a1.z += x1.x*v0.z + x1.y*v1.z + x1.z*v2.z + x1.w*v3.z;
            a1.w += x1.x*v0.w + x1.y*v1.w + x1.z*v2.w + x1.w*v3.w;

            a2.x += x2.x*v0.x + x2.y*v1.x + x2.z*v2.x + x2.w*v3.x;
            a2.y += x2.x*v0.y + x2.y*v1.y + x2.z*v2.y + x2.w*v3.y;
            a2.z += x2.x*v0.z + x2.y*v1.z + x2.z*v2.z + x2.w*v3.z;
            a2.w += x2.x*v0.w + x2.y*v1.w + x2.z*v2.w + x2.w*v3.w;

            a3.x += x3.x*v0.x + x3.y*v1.x + x3.z*v2.x + x3.w*v3.x;
            a3.y += x3.x*v0.y + x3.y*v1.y + x3.z*v2.y + x3.w*v3.y;
            a3.z += x3.x*v0.z + x3.y*v1.z + x3.z*v2.z + x3.w*v3.z;
            a3.w += x3.x*v0.w + x3.y*v1.w + x3.z*v2.w + x3.w*v3.w;

            if (ksub == 0) {
                const float4 wq = *(const float4*)&wL[n0];
                l0 += x0.x*wq.x + x0.y*wq.y + x0.z*wq.z + x0.w*wq.w;
                l1 += x1.x*wq.x + x1.y*wq.y + x1.z*wq.z + x1.w*wq.w;
                l2 += x2.x*wq.x + x2.y*wq.y + x2.z*wq.z + x2.w*wq.w;
                l3 += x3.x*wq.x + x3.y*wq.y + x3.z*wq.z + x3.w*wq.w;
            }
        }
        asm volatile("" ::: "memory");
        __builtin_amdgcn_s_barrier();   // reads of buf p done; overwrite ok
        asm volatile("" ::: "memory");
    }

    // xv writes: 4 rows x float4, coalesced (1 KB contiguous per wave per row-set)
    {
        float* base = xv + ((size_t)b * M_ + m0 + rs) * K_ + ksub * 4;
        *(float4*)(base +   0 * K_) = a0;
        *(float4*)(base +  64 * K_) = a1;
        *(float4*)(base + 128 * K_) = a2;
        *(float4*)(base + 192 * K_) = a3;
    }
    if (ksub == 0) {
        float* ob = out + (size_t)b * M_ + m0 + rs;
        ob[0]   = l0 + bias0;
        ob[64]  = l1 + bias0;
        ob[128] = l2 + bias0;
        ob[192] = l3 + bias0;
    }

    // sv: local 4-row sum, butterfly over rs bits (4,8,16,32), cross-wave via LDS
    float4 s = {a0.x + a1.x + a2.x + a3.x,
                a0.y + a1.y + a2.y + a3.y,
                a0.z + a1.z + a2.z + a3.z,
                a0.w + a1.w + a2.w + a3.w};
    #pragma unroll
    for (int off = 4; off < 64; off <<= 1) {
        s.x += __shfl_xor(s.x, off);
        s.y += __shfl_xor(s.y, off);
        s.z += __shfl_xor(s.z, off);
        s.w += __shfl_xor(s.w, off);
    }
    const int wave = t >> 6;
    if ((t & 63) < 4)
        *(float4*)(red + wave * 16 + ksub * 4) = s;
    __syncthreads();
    if (t < 16)
        svpart[(size_t)blk * 16 + t] = red[t] + red[16 + t] + red[32 + t] + red[48 + t];
}

// ---------------- Pass 2 ----------------
// grid = B_*2 blocks, 256 threads; thread per row.
__global__ __launch_bounds__(256) void fm_pass2(
    const float* __restrict__ xv, const float* __restrict__ svpart,
    float* __restrict__ out)
{
    const int t = threadIdx.x;
    const int blk = blockIdx.x;
    const int b = blk >> 1;
    const int m = (blk & 1) * 256 + t;
    __shared__ __align__(16) float svL[16];
    if (t < 16)
        svL[t] = svpart[(size_t)(b * 2 + 0) * 16 + t] + svpart[(size_t)(b * 2 + 1) * 16 + t];
    __syncthreads();

    const float4* xvp = (const float4*)(xv + ((size_t)b * M_ + m) * K_);
    float4 a0 = xvp[0], a1 = xvp[1], a2 = xvp[2], a3 = xvp[3];
    const float4* s4 = (const float4*)svL;
    float4 s0 = s4[0], s1 = s4[1], s2 = s4[2], s3 = s4[3];

    float rs = a0.x * s0.x + a0.y * s0.y + a0.z * s0.z + a0.w * s0.w
             + a1.x * s1.x + a1.y * s1.y + a1.z * s1.z + a1.w * s1.w
             + a2.x * s2.x + a2.y * s2.y + a2.z * s2.z + a2.w * s2.w
             + a3.x * s3.x + a3.y * s3.y + a3.z * s3.z + a3.w * s3.w;
    float dg = a0.x * a0.x + a0.y * a0.y + a0.z * a0.z + a0.w * a0.w
             + a1.x * a1.x + a1.y * a1.y + a1.z * a1.z + a1.w * a1.w
             + a2.x * a2.x + a2.y * a2.y + a2.z * a2.z + a2.w * a2.w
             + a3.x * a3.x + a3.y * a3.y + a3.z * a3.z + a3.w * a3.w;

    const size_t o = (size_t)b * M_ + m;
    out[o] = out[o] + 0.5f * (rs - dg);
}

extern "C" void kernel_launch(void* const* d_in, const int* in_sizes, int n_in,
                              void* d_out, int out_size, void* d_ws, size_t ws_size,
                              hipStream_t stream) {
    const float* x    = (const float*)d_in[0];
    const float* w    = (const float*)d_in[1];
    const float* bias = (const float*)d_in[2];
    const float* v    = (const float*)d_in[3];
    float* out = (float*)d_out;

    float* xv     = (float*)d_ws;                 // B*M*K floats = 8 MiB
    float* svpart = xv + (size_t)B_ * M_ * K_;    // 512*16 floats

    fm_pass1<<<dim3(B_ * 2), dim3(256), 0, stream>>>(x, w, bias, v, xv, svpart, out);
    fm_pass2<<<dim3(B_ * 2), dim3(256), 0, stream>>>(xv, svpart, out);
}